// Round 3
// baseline (774.265 us; speedup 1.0000x reference)
//
#include <hip/hip_runtime.h>
#include <hip/hip_bf16.h>
#include <stdint.h>
#include <type_traits>

// Problem constants: B=256, T=512, D=300, H=128, 4H=512, C=6
#define NB 256
#define NT 512
#define ND 300
#define NH 128
#define NG 512
#define NC 6

typedef __attribute__((ext_vector_type(8))) short short8;
typedef __attribute__((ext_vector_type(4))) float f32x4;

static __device__ __forceinline__ float bf2f(unsigned int u) {
  return __builtin_bit_cast(float, (u & 0xffffu) << 16);
}
static __device__ __forceinline__ unsigned short f2bf(float f) {
  return __builtin_bit_cast(unsigned short, __float2bfloat16(f));
}
static __device__ __forceinline__ unsigned int packbf(float a, float b) {
  return (unsigned int)f2bf(a) | ((unsigned int)f2bf(b) << 16);
}
static __device__ __forceinline__ float ld1(const unsigned short* p) { return bf2f(*p); }
static __device__ __forceinline__ float ld1(const float* p) { return *p; }
static __device__ __forceinline__ void st1(unsigned short* p, float v) { *p = f2bf(v); }
static __device__ __forceinline__ void st1(float* p, float v) { *p = v; }

static __device__ __forceinline__ float sigmoid_fast(float x) {
  return __builtin_amdgcn_rcpf(1.f + __expf(-x));
}
static __device__ __forceinline__ float tanh_fast(float x) {
  return 1.f - 2.f * __builtin_amdgcn_rcpf(__expf(2.f * x) + 1.f);
}

// Barrier that does NOT drain vmcnt: LDS ordering only. Global-load
// prefetches stay in flight across it (T4 counted-vmcnt idiom); the
// compiler still inserts register-dependency vmcnt waits at first use.
#define BARRIER_LGKM() asm volatile("s_waitcnt lgkmcnt(0)\n\ts_barrier" ::: "memory")

// ---- staging loads: 4 K-elems -> 2 packed bf16 pairs ------------------------
static __device__ __forceinline__ uint2 load4bf_fast(const unsigned short* row, int k) {
  return *(const uint2*)(row + k);  // 8B-aligned (k%4==0, row stride 600B)
}
static __device__ __forceinline__ uint2 load4bf_fast(const float* row, int k) {
  float4 f = *(const float4*)(row + k);  // 16B-aligned (k%4==0, row stride 1200B)
  uint2 v;
  v.x = packbf(f.x, f.y);
  v.y = packbf(f.z, f.w);
  return v;
}
static __device__ __forceinline__ uint2 load4bf(const unsigned short* row, int k, int lim) {
  if (k + 3 < lim) return load4bf_fast(row, k);
  unsigned int e0 = (k + 0 < lim) ? row[k + 0] : 0;
  unsigned int e1 = (k + 1 < lim) ? row[k + 1] : 0;
  unsigned int e2 = (k + 2 < lim) ? row[k + 2] : 0;
  unsigned int e3 = (k + 3 < lim) ? row[k + 3] : 0;
  uint2 v;
  v.x = e0 | (e1 << 16);
  v.y = e2 | (e3 << 16);
  return v;
}
static __device__ __forceinline__ uint2 load4bf(const float* row, int k, int lim) {
  if (k + 3 < lim) return load4bf_fast(row, k);
  float f0 = (k + 0 < lim) ? row[k + 0] : 0.f;
  float f1 = (k + 1 < lim) ? row[k + 1] : 0.f;
  float f2 = (k + 2 < lim) ? row[k + 2] : 0.f;
  float f3 = (k + 3 < lim) ? row[k + 3] : 0.f;
  uint2 v;
  v.x = packbf(f0, f1);
  v.y = packbf(f2, f3);
  return v;
}

// ---------------------------------------------------------------------------
// Dtype detector (flag: 0 = bf16 inputs, 1 = fp32 inputs).
// ---------------------------------------------------------------------------
__global__ void detect_dtype(const unsigned short* __restrict__ X, int* __restrict__ flag) {
  __shared__ int cnt;
  if (threadIdx.x == 0) cnt = 0;
  __syncthreads();
  int c = 0;
  for (int i = threadIdx.x; i < 512; i += 64) {
    unsigned int u = X[i];
    unsigned int e = (u >> 7) & 0xffu;
    if (u == 0u || (e >= 97u && e <= 157u)) c++;
  }
  atomicAdd(&cnt, c);
  __syncthreads();
  if (threadIdx.x == 0) *flag = (cnt >= 448) ? 0 : 1;
}

// ---------------------------------------------------------------------------
// W_ih pre-pack: fragment-ordered bf16, zero-padded K to 320.
// Layout: Wpre[rtg(32)][chunk(10)][lane(64)][8 bf16], where the short8 at
// (rtg, c, l) = W_ih[rtg*16 + (l&15)][c*32 + (l>>4)*8 + j]  (0 for k>=300).
// The fused kernel's A-fragment load is then ONE coalesced 16B/lane read.
// ---------------------------------------------------------------------------
template <typename XT>
__global__ __launch_bounds__(256) void wprep(const int* __restrict__ flag, int want,
                                             const XT* __restrict__ Wih,
                                             unsigned short* __restrict__ Wpre) {
  if (*flag != want) return;
  const int i = blockIdx.x * 256 + threadIdx.x;  // 0..20479 (= 32*10*64)
  const int rtg = i / 640;
  const int rem = i % 640;
  const int c = rem >> 6;
  const int l2 = rem & 63;
  const int row = rtg * 16 + (l2 & 15);
  const int kb = c * 32 + (l2 >> 4) * 8;
  union { unsigned short v[8]; short8 s; } o;
#pragma unroll
  for (int j = 0; j < 8; ++j) {
    const int k = kb + j;
    o.v[j] = (k < ND) ? f2bf(ld1(Wih + (size_t)row * ND + k)) : (unsigned short)0;
  }
  *(short8*)(Wpre + (size_t)i * 8) = o.s;
}

// ---------------------------------------------------------------------------
// FUSED kernel: gx-GEMM + LSTM recurrence + FC, one block per batch.
//
// Rationale (round 3): the split pipeline materialized gx (268 MB f32) to
// global: gx_gemm (~250-300us, bound by serial x-read + W-L2-restream +
// 268MB write) then lstm_rec (267us, latency-bound at ~1250 cyc/step with
// MfmaUtil 19% / VALUBusy 26% -- i.e. 75% idle issue slots). The per-batch
// x-GEMM is only 157 MFLOP = ~2.5 MFMA + ~8 loads per step per wave: it
// fits entirely in the recurrence's idle shadow. So window w+1's gates
// (16 steps x 512 gates, f32) are computed into LDS while the recurrence
// consumes window w. gx never touches global memory.
//
// Schedule per full window w (16 steps, roles are block-uniform):
//   st 0..9   : issue W-frag loads chunk st (dbuf slots), MFMA chunk st-1
//   st 10     : MFMA chunk 9
//   st 11..14 : +bias, write gw[(w+1)&1] quarter rt = st-11
//   st 0 / 8  : issue x-loads / LDS-write xw[(w+2)&1] (window w+2)
// One lgkm-only barrier per step (global loads float across it).
// Buffers: gw dbuf (f32 gates), xw dbuf (bf16 x window), hpk dbuf (h).
// LDS = 66.5K (gw) + 21K (xw) + 1K = ~89 KB -> 1 block/CU, 8 waves.
// Rec math is bit-identical to round 2 (same MFMA order, same gate math).
// ---------------------------------------------------------------------------

#define ISSUE_A(cc, ss)                                                         \
  do {                                                                          \
    if constexpr (WPRE) {                                                       \
      _Pragma("unroll") for (int rt = 0; rt < 4; ++rt)                          \
          sA##ss[rt] = *(const short8*)(Wpre +                                  \
              (size_t)((((w8 << 2) + rt) * 10 + (cc)) * 64 + l) * 8);           \
    } else {                                                                    \
      _Pragma("unroll") for (int rt = 0; rt < 4; ++rt) {                        \
        const XT* wr_ = Wih + (size_t)(w8 * 64 + rt * 16 + lr) * ND;            \
        uA##ss[rt][0] = load4bf(wr_, (cc) * 32 + lq * 8, ND);                   \
        uA##ss[rt][1] = load4bf(wr_, (cc) * 32 + lq * 8 + 4, ND);               \
      }                                                                         \
    }                                                                           \
  } while (0)

#define CONSUME_A(cc, ss)                                                       \
  do {                                                                          \
    const short8 bfrG_ = *(const short8*)&xb1[lr][(cc) * 32 + lq * 8];          \
    _Pragma("unroll") for (int rt = 0; rt < 4; ++rt) {                          \
      short8 a_;                                                                \
      if constexpr (WPRE) {                                                     \
        a_ = sA##ss[rt];                                                        \
      } else {                                                                  \
        union { uint2 u2[2]; short8 s; } cv_;                                   \
        cv_.u2[0] = uA##ss[rt][0];                                              \
        cv_.u2[1] = uA##ss[rt][1];                                              \
        a_ = cv_.s;                                                             \
      }                                                                         \
      accG[rt] = __builtin_amdgcn_mfma_f32_16x16x32_bf16(a_, bfrG_, accG[rt],   \
                                                         0, 0, 0);              \
    }                                                                           \
  } while (0)

#define WRITEBACK_RT(rt_)                                                       \
  do {                                                                          \
    f32x4 o_;                                                                   \
    _Pragma("unroll") for (int rg = 0; rg < 4; ++rg)                            \
        o_[rg] = accG[rt_][rg] + biasr[rt_][rg];                                \
    *(f32x4*)&gb1[lr][w8 * 64 + (rt_) * 16 + lq * 4] = o_;                      \
  } while (0)

template <typename XT, bool WPRE>
__global__ __launch_bounds__(512)
__attribute__((amdgpu_waves_per_eu(2, 2)))
void lstm_fused(const int* __restrict__ flag, int want,
                const XT* __restrict__ X,
                const XT* __restrict__ Wih,
                const XT* __restrict__ Whh,
                const XT* __restrict__ bih,
                const XT* __restrict__ bhh,
                const XT* __restrict__ fcw,
                const XT* __restrict__ fcb,
                const int* __restrict__ lengths,
                XT* __restrict__ out,
                const unsigned short* __restrict__ Wpre) {
  if (*flag != want) return;
  const int b = blockIdx.x;
  int len = lengths[b];
  if (len > NT) len = NT;
  if (len < 0) len = 0;
  const int nwin = (len + 15) >> 4;

  // gw rows padded to 520 (520 % 32 == 8 -> writeback 4-way not 16-way);
  // xw rows padded to 328 (164 dw % 32 == 4 -> B-frag reads ~2-way).
  __shared__ __align__(16) float gw[2][16][520];           // 66.5 KB gates (f32!)
  __shared__ __align__(16) unsigned short xw[2][16][328];  // 21 KB x window bf16
  __shared__ __align__(16) unsigned short hpk[2][NH];      // packed bf16 h, dbuf
  __shared__ __align__(16) float hf[NH];                   // final h (FC epilogue)

  const int tid = threadIdx.x;
  const int w8 = tid >> 6;         // wave
  const int l = tid & 63;
  const int q = l >> 4;            // quad group
  const int m = l & 15;
  const int lq = q;
  const int lr = m;
  const int u0 = w8 * 16 + q * 4;  // rec: first unit of this lane's D rows
  const int r = m & 3;             // rec: unit handled by this lane
  const int u = u0 + r;

  // ---- rec A fragments: afr[g][c] = W_hh[g*128 + w8*16 + m][c*32 + q*8 ..]
  short8 afr[4][4];
#pragma unroll
  for (int g = 0; g < 4; ++g) {
    const int row = g * NH + w8 * 16 + m;
    if constexpr (std::is_same_v<XT, unsigned short>) {
#pragma unroll
      for (int c = 0; c < 4; ++c)
        afr[g][c] = *(const short8*)(Whh + (size_t)row * NH + c * 32 + q * 8);
    } else {
#pragma unroll
      for (int c = 0; c < 4; ++c) {
        const float* p = Whh + (size_t)row * NH + c * 32 + q * 8;
        float4 f0 = *(const float4*)p;
        float4 f1 = *(const float4*)(p + 4);
        union { unsigned int uu[4]; short8 s; } cv2;
        cv2.uu[0] = packbf(f0.x, f0.y);
        cv2.uu[1] = packbf(f0.z, f0.w);
        cv2.uu[2] = packbf(f1.x, f1.y);
        cv2.uu[3] = packbf(f1.z, f1.w);
        afr[g][c] = cv2.s;
      }
    }
  }

  // ---- GEMM bias registers: gate row = w8*64 + rt*16 + lq*4 + rg
  float biasr[4][4];
#pragma unroll
  for (int rt = 0; rt < 4; ++rt)
#pragma unroll
    for (int rg = 0; rg < 4; ++rg) {
      const int g = w8 * 64 + rt * 16 + lq * 4 + rg;
      biasr[rt][rg] = ld1(bih + g) + ld1(bhh + g);
    }

  // ---- zero-fill xw pad columns 300..327 (both buffers, once) ------------
  if (tid < 448) {
    const int bi = tid / 224;
    const int rr = (tid % 224) / 14;
    const int cc = 300 + (tid % 14) * 2;
    *(unsigned int*)&xw[bi][rr][cc] = 0u;
  }

  // ---- stage x window 0 ---------------------------------------------------
  if (nwin > 0) {
#pragma unroll
    for (int ii = 0; ii < 3; ++ii) {
      const int j = tid + ii * 512;
      if (j < 1200) {
        const int row = j / 75, col = (j % 75) * 4;
        const XT* src = X + ((size_t)b * NT + row) * ND + col;
        *(uint2*)&xw[0][row][col] = load4bf_fast(src, 0);
      }
    }
  }
  __syncthreads();

  // ---- GEMM state shared by prologue + step roles (via macros) -----------
  short8 sA0[4], sA1[4];
  uint2 uA0[4][2], uA1[4][2];
  f32x4 accG[4];
  unsigned short (*xb1)[328] = xw[0];
  float (*gb1)[520] = gw[0];

  // ---- prologue: GEMM window 0 -> gw[0] ----------------------------------
  if (nwin > 0) {
#pragma unroll
    for (int rt = 0; rt < 4; ++rt) { f32x4 z = {0.f, 0.f, 0.f, 0.f}; accG[rt] = z; }
    ISSUE_A(0, 0);
    ISSUE_A(1, 1); CONSUME_A(0, 0);
    ISSUE_A(2, 0); CONSUME_A(1, 1);
    ISSUE_A(3, 1); CONSUME_A(2, 0);
    ISSUE_A(4, 0); CONSUME_A(3, 1);
    ISSUE_A(5, 1); CONSUME_A(4, 0);
    ISSUE_A(6, 0); CONSUME_A(5, 1);
    ISSUE_A(7, 1); CONSUME_A(6, 0);
    ISSUE_A(8, 0); CONSUME_A(7, 1);
    ISSUE_A(9, 1); CONSUME_A(8, 0);
    CONSUME_A(9, 1);
    WRITEBACK_RT(0); WRITEBACK_RT(1); WRITEBACK_RT(2); WRITEBACK_RT(3);
  }

  // ---- stage x window 1 ---------------------------------------------------
  if (nwin > 1) {
#pragma unroll
    for (int ii = 0; ii < 3; ++ii) {
      const int j = tid + ii * 512;
      if (j < 1200) {
        const int row = j / 75, col = (j % 75) * 4;
        const XT* src = X + ((size_t)b * NT + 16 + row) * ND + col;
        *(uint2*)&xw[1][row][col] = load4bf_fast(src, 0);
      }
    }
  }

  float hcur = 0.f, ccur = 0.f;
  if (m < 4) hpk[0][u] = f2bf(0.f);
  __syncthreads();

  // ---- main loop: windows of 16 steps ------------------------------------
  for (int w = 0; w < nwin; ++w) {
    const int rem = len - w * 16;
    const int tlim = (rem < 16) ? rem : 16;
    const bool gemm_on = (w + 1 < nwin);   // only last window is partial, so
    const bool stage_on = (w + 2 < nwin);  // roles never coincide with break
    float (*gb0)[520] = gw[w & 1];
    xb1 = xw[(w + 1) & 1];
    gb1 = gw[(w + 1) & 1];
    if (gemm_on) {
#pragma unroll
      for (int rt = 0; rt < 4; ++rt) { f32x4 z = {0.f, 0.f, 0.f, 0.f}; accG[rt] = z; }
    }
    float4 rf[3];
    uint2 ru[3];

#pragma unroll 4
    for (int st = 0; st < 16; ++st) {
      if (st >= tlim) break;

      // ---- recurrence step (math identical to round 2) ----
      float g_c[4];
#pragma unroll
      for (int g = 0; g < 4; ++g) g_c[g] = gb0[st][g * 128 + u];
      short8 bfr[4];
      const unsigned short* hrow = hpk[st & 1];
#pragma unroll
      for (int c = 0; c < 4; ++c) bfr[c] = *(const short8*)&hrow[c * 32 + q * 8];
      f32x4 acc[4];
#pragma unroll
      for (int g = 0; g < 4; ++g) {
        f32x4 z = {0.f, 0.f, 0.f, 0.f};
        acc[g] = z;
#pragma unroll
        for (int c = 0; c < 4; ++c)
          acc[g] = __builtin_amdgcn_mfma_f32_16x16x32_bf16(afr[g][c], bfr[c], acc[g], 0, 0, 0);
      }
      float pre[4];
#pragma unroll
      for (int g = 0; g < 4; ++g) {
        const float t0v = (r & 1) ? acc[g][1] : acc[g][0];
        const float t1v = (r & 1) ? acc[g][3] : acc[g][2];
        pre[g] = ((r & 2) ? t1v : t0v) + g_c[g];
      }
      const float ig = sigmoid_fast(pre[0]);
      const float fg = sigmoid_fast(pre[1]);
      const float gg = tanh_fast(pre[2]);
      const float og = sigmoid_fast(pre[3]);
      ccur = fmaf(fg, ccur, ig * gg);
      hcur = og * tanh_fast(ccur);
      if (m < 4) hpk[(st + 1) & 1][u] = f2bf(hcur);

      // ---- GEMM role: window w+1 ----
      if (gemm_on) {
        if (st == 0) { ISSUE_A(0, 0); }
        if (st == 1) { ISSUE_A(1, 1); CONSUME_A(0, 0); }
        if (st == 2) { ISSUE_A(2, 0); CONSUME_A(1, 1); }
        if (st == 3) { ISSUE_A(3, 1); CONSUME_A(2, 0); }
        if (st == 4) { ISSUE_A(4, 0); CONSUME_A(3, 1); }
        if (st == 5) { ISSUE_A(5, 1); CONSUME_A(4, 0); }
        if (st == 6) { ISSUE_A(6, 0); CONSUME_A(5, 1); }
        if (st == 7) { ISSUE_A(7, 1); CONSUME_A(6, 0); }
        if (st == 8) { ISSUE_A(8, 0); CONSUME_A(7, 1); }
        if (st == 9) { ISSUE_A(9, 1); CONSUME_A(8, 0); }
        if (st == 10) { CONSUME_A(9, 1); }
        if (st == 11) { WRITEBACK_RT(0); }
        if (st == 12) { WRITEBACK_RT(1); }
        if (st == 13) { WRITEBACK_RT(2); }
        if (st == 14) { WRITEBACK_RT(3); }
      }

      // ---- stage role: x window w+2 (issue early, LDS-write late) ----
      if (stage_on) {
        if (st == 0) {
#pragma unroll
          for (int ii = 0; ii < 3; ++ii) {
            const int j = tid + ii * 512;
            if (j < 1200) {
              const int row = j / 75, col = (j % 75) * 4;
              const XT* src = X + ((size_t)b * NT + (w + 2) * 16 + row) * ND + col;
              if constexpr (std::is_same_v<XT, float>) rf[ii] = *(const float4*)src;
              else ru[ii] = *(const uint2*)src;
            }
          }
        }
        if (st == 8) {
#pragma unroll
          for (int ii = 0; ii < 3; ++ii) {
            const int j = tid + ii * 512;
            if (j < 1200) {
              const int row = j / 75, col = (j % 75) * 4;
              uint2 v;
              if constexpr (std::is_same_v<XT, float>) {
                v.x = packbf(rf[ii].x, rf[ii].y);
                v.y = packbf(rf[ii].z, rf[ii].w);
              } else {
                v = ru[ii];
              }
              *(uint2*)&xw[w & 1][row][col] = v;  // (w+2)&1 == w&1
            }
          }
        }
      }

      BARRIER_LGKM();
    }
  }

  // ---- FC epilogue --------------------------------------------------------
  if (m < 4) hf[u] = hcur;
  __syncthreads();
  if (tid < NC) {
    float acc = ld1(fcb + tid);
    const XT* wv = fcw + (size_t)tid * NH;
#pragma unroll
    for (int k = 0; k < NH; ++k) acc = fmaf(ld1(wv + k), hf[k], acc);
    st1(out + (size_t)b * NC + tid, acc);
  }
}

#undef ISSUE_A
#undef CONSUME_A
#undef WRITEBACK_RT

// ---------------------------------------------------------------------------
extern "C" void kernel_launch(void* const* d_in, const int* in_sizes, int n_in,
                              void* d_out, int out_size, void* d_ws, size_t ws_size,
                              hipStream_t stream) {
  int* flag = (int*)d_ws;
  detect_dtype<<<dim3(1), dim3(64), 0, stream>>>((const unsigned short*)d_in[0], flag);

  unsigned short* wsW = (unsigned short*)((char*)d_ws + 512);
  const size_t wpre_bytes = (size_t)32 * 10 * 64 * 8 * 2;  // 320 KB
  const bool use_pre = ws_size >= 512 + wpre_bytes;

  const unsigned short* Xu = (const unsigned short*)d_in[0];
  const float* Xf = (const float*)d_in[0];

  if (use_pre) {
    wprep<unsigned short><<<dim3(80), dim3(256), 0, stream>>>(
        flag, 0, (const unsigned short*)d_in[1], wsW);
    wprep<float><<<dim3(80), dim3(256), 0, stream>>>(
        flag, 1, (const float*)d_in[1], wsW);
    lstm_fused<unsigned short, true><<<dim3(NB), dim3(512), 0, stream>>>(
        flag, 0, Xu, (const unsigned short*)d_in[1], (const unsigned short*)d_in[2],
        (const unsigned short*)d_in[3], (const unsigned short*)d_in[4],
        (const unsigned short*)d_in[5], (const unsigned short*)d_in[6],
        (const int*)d_in[7], (unsigned short*)d_out, wsW);
    lstm_fused<float, true><<<dim3(NB), dim3(512), 0, stream>>>(
        flag, 1, Xf, (const float*)d_in[1], (const float*)d_in[2],
        (const float*)d_in[3], (const float*)d_in[4], (const float*)d_in[5],
        (const float*)d_in[6], (const int*)d_in[7], (float*)d_out, wsW);
  } else {
    lstm_fused<unsigned short, false><<<dim3(NB), dim3(512), 0, stream>>>(
        flag, 0, Xu, (const unsigned short*)d_in[1], (const unsigned short*)d_in[2],
        (const unsigned short*)d_in[3], (const unsigned short*)d_in[4],
        (const unsigned short*)d_in[5], (const unsigned short*)d_in[6],
        (const int*)d_in[7], (unsigned short*)d_out, nullptr);
    lstm_fused<float, false><<<dim3(NB), dim3(512), 0, stream>>>(
        flag, 1, Xf, (const float*)d_in[1], (const float*)d_in[2],
        (const float*)d_in[3], (const float*)d_in[4], (const float*)d_in[5],
        (const float*)d_in[6], (const int*)d_in[7], (float*)d_out, nullptr);
  }
}

// Round 4
// 710.299 us; speedup vs baseline: 1.0901x; 1.0901x over previous
//
#include <hip/hip_runtime.h>
#include <hip/hip_bf16.h>
#include <stdint.h>
#include <type_traits>

// Problem constants: B=256, T=512, D=300, H=128, 4H=512, C=6
#define NB 256
#define NT 512
#define ND 300
#define NH 128
#define NG 512
#define NC 6

typedef __attribute__((ext_vector_type(8))) short short8;
typedef __attribute__((ext_vector_type(4))) float f32x4;

static __device__ __forceinline__ float bf2f(unsigned int u) {
  return __builtin_bit_cast(float, (u & 0xffffu) << 16);
}
static __device__ __forceinline__ unsigned short f2bf(float f) {
  return __builtin_bit_cast(unsigned short, __float2bfloat16(f));
}
static __device__ __forceinline__ unsigned int packbf(float a, float b) {
  return (unsigned int)f2bf(a) | ((unsigned int)f2bf(b) << 16);
}
static __device__ __forceinline__ float ld1(const unsigned short* p) { return bf2f(*p); }
static __device__ __forceinline__ float ld1(const float* p) { return *p; }
static __device__ __forceinline__ void st1(unsigned short* p, float v) { *p = f2bf(v); }
static __device__ __forceinline__ void st1(float* p, float v) { *p = v; }

static __device__ __forceinline__ float sigmoid_fast(float x) {
  return __builtin_amdgcn_rcpf(1.f + __expf(-x));
}
static __device__ __forceinline__ float tanh_fast(float x) {
  return 1.f - 2.f * __builtin_amdgcn_rcpf(__expf(2.f * x) + 1.f);
}

// Barrier that does NOT drain vmcnt: LDS ordering only. Global-load
// prefetches stay in flight across it (T4 counted-vmcnt idiom); the
// compiler still inserts register-dependency vmcnt waits at first use.
#define BARRIER_LGKM() asm volatile("s_waitcnt lgkmcnt(0)\n\ts_barrier" ::: "memory")

// ---- staging loads: 4 K-elems -> 2 packed bf16 pairs ------------------------
static __device__ __forceinline__ uint2 load4bf_fast(const unsigned short* row, int k) {
  return *(const uint2*)(row + k);  // 8B-aligned (k%4==0, row stride 600B)
}
static __device__ __forceinline__ uint2 load4bf_fast(const float* row, int k) {
  float4 f = *(const float4*)(row + k);  // 16B-aligned (k%4==0, row stride 1200B)
  uint2 v;
  v.x = packbf(f.x, f.y);
  v.y = packbf(f.z, f.w);
  return v;
}
static __device__ __forceinline__ uint2 load4bf(const unsigned short* row, int k, int lim) {
  if (k + 3 < lim) return load4bf_fast(row, k);
  unsigned int e0 = (k + 0 < lim) ? row[k + 0] : 0;
  unsigned int e1 = (k + 1 < lim) ? row[k + 1] : 0;
  unsigned int e2 = (k + 2 < lim) ? row[k + 2] : 0;
  unsigned int e3 = (k + 3 < lim) ? row[k + 3] : 0;
  uint2 v;
  v.x = e0 | (e1 << 16);
  v.y = e2 | (e3 << 16);
  return v;
}
static __device__ __forceinline__ uint2 load4bf(const float* row, int k, int lim) {
  if (k + 3 < lim) return load4bf_fast(row, k);
  float f0 = (k + 0 < lim) ? row[k + 0] : 0.f;
  float f1 = (k + 1 < lim) ? row[k + 1] : 0.f;
  float f2 = (k + 2 < lim) ? row[k + 2] : 0.f;
  float f3 = (k + 3 < lim) ? row[k + 3] : 0.f;
  uint2 v;
  v.x = packbf(f0, f1);
  v.y = packbf(f2, f3);
  return v;
}

// ---------------------------------------------------------------------------
// Per-block dtype self-detect (0 = bf16 inputs, 1 = fp32 inputs).
// Replaces the separate detect kernel + dead-variant launches: every block
// inspects X[0..511] (1 KB, L2-hot after the first block) and runtime-
// dispatches the typed body. Launch count drops 5 -> 2 per iteration.
// ---------------------------------------------------------------------------
static __device__ __forceinline__ int block_detect(const unsigned short* __restrict__ X,
                                                   int* cnt) {
  const int tid = threadIdx.x;
  const int nthr = blockDim.x;
  if (tid == 0) *cnt = 0;
  __syncthreads();
  int c = 0;
  for (int i = tid; i < 512; i += nthr) {
    unsigned int u = X[i];
    unsigned int e = (u >> 7) & 0xffu;
    if (u == 0u || (e >= 97u && e <= 157u)) c++;
  }
  if (c) atomicAdd(cnt, c);
  __syncthreads();
  return (*cnt >= 448) ? 0 : 1;
}

// ---------------------------------------------------------------------------
// Phase 1 body: gx[m][n] = sum_k x[b,t,k] * W_ih[n][k] + (bih[n]+bhh[n]).
// Round-2 structure (best measured): M-tile 64, full-K A staged once
// (As[10][64][40], 50 KB), W double-buffered per 32-K chunk with lgkm-only
// barriers and distance-3 register prefetch. LDS passed in (shared between
// the two runtime dtype paths so the block's footprint stays 70 KB).
// ---------------------------------------------------------------------------
template <typename XT, typename GXT>
static __device__ __forceinline__ void gx_body(
    const XT* __restrict__ X, const XT* __restrict__ Wih,
    const XT* __restrict__ bih, const XT* __restrict__ bhh,
    const int* __restrict__ lengths, GXT* __restrict__ gx,
    int b_base, int t_base, int Tc, unsigned short* smem) {
  auto As = reinterpret_cast<unsigned short(*)[64][40]>(smem);           // [10][64][40]
  auto Bs = reinterpret_cast<unsigned short(*)[128][40]>(smem + 25600);  // [2][128][40]

  const int mb = blockIdx.x;
  const int m0 = mb << 6;  // 64 rows per block
  const int bc = m0 / Tc;
  const int trel0 = m0 % Tc;
  const int b = b_base + bc;
  const int t0 = t_base + trel0;
  const int len = lengths[b];
  if (t0 >= len) return;  // block-uniform

  const int tid = threadIdx.x;
  const int lane = tid & 63;
  const int wave = tid >> 6;
  const int wm = wave & 1;   // M strip of 32
  const int wn = wave >> 1;  // N strip of 64 (within 128-col pass)
  const int lq = lane >> 4;
  const int lr = lane & 15;

  // ---- Prologue: stage A (64 rows x 320 k) once --------------------------
  const int rA = tid >> 2;
  const int cA = (tid & 3) << 2;  // 0,4,8,12
  const XT* xrow = X + ((size_t)b * NT + t0 + rA) * ND;
  {
    uint2 a0[10], a1[10];
#pragma unroll
    for (int kc = 0; kc < 9; ++kc) {
      a0[kc] = load4bf_fast(xrow, kc * 32 + cA);
      a1[kc] = load4bf_fast(xrow, kc * 32 + 16 + cA);
    }
    a0[9] = load4bf(xrow, 288 + cA, ND);       // 288..303 masked at 300
    a1[9] = load4bf(xrow, 288 + 16 + cA, ND);  // 304..319 all masked
#pragma unroll
    for (int kc = 0; kc < 10; ++kc) {
      *(uint2*)&As[kc][rA][cA] = a0[kc];
      *(uint2*)&As[kc][rA][16 + cA] = a1[kc];
    }
  }

  // ---- W stream: 8 lanes per row (coalesced 128B/row segments) -----------
  const int rb = tid >> 3;  // 0..31; thread covers rows rb+32j, j=0..3
  const int kq = tid & 7;   // k offset kq*4 within the 32-k chunk

  // 3-slot register prefetch: chunk m of current pass lives in bv[m%3].
  uint2 bv[3][4];
  {
    const XT* wb = Wih + (size_t)rb * ND;  // pass 0 (n0 = 0)
#pragma unroll
    for (int s3 = 0; s3 < 3; ++s3)
#pragma unroll
      for (int j = 0; j < 4; ++j)
        bv[s3][j] = load4bf_fast(wb + (size_t)(32 * j) * ND, s3 * 32 + kq * 4);
  }

  for (int nt = 0; nt < 4; ++nt) {
    const int n0 = nt << 7;
    const XT* wb = Wih + (size_t)(n0 + rb) * ND;

    f32x4 acc[2][4];
#pragma unroll
    for (int i = 0; i < 2; ++i)
#pragma unroll
      for (int j = 0; j < 4; ++j) {
        f32x4 z = {0.f, 0.f, 0.f, 0.f};
        acc[i][j] = z;
      }

    // write chunk 0 (Bs[0] readers of prev pass finished at its kc=8 barrier;
    // at nt=0 the barrier below also publishes the A staging)
#pragma unroll
    for (int j = 0; j < 4; ++j) *(uint2*)&Bs[0][rb + 32 * j][kq * 4] = bv[0][j];
    BARRIER_LGKM();

#pragma unroll
    for (int kc = 0; kc < 10; ++kc) {
      const int bi = kc & 1;
      // stage chunk kc+1 (loaded at chunk kc-2 -> ~2 bodies of slack)
      if (kc < 9) {
#pragma unroll
        for (int j = 0; j < 4; ++j)
          *(uint2*)&Bs[bi ^ 1][rb + 32 * j][kq * 4] = bv[(kc + 1) % 3][j];
      }
      // prefetch chunk kc+3 into the slot freed by chunk kc's LDS-write
      if (kc < 7) {
        const int kn = (kc + 3) * 32 + kq * 4;
        if (kc < 6) {
#pragma unroll
          for (int j = 0; j < 4; ++j)
            bv[kc % 3][j] = load4bf_fast(wb + (size_t)(32 * j) * ND, kn);
        } else {  // chunk 9: k 288..319 masked at 300
#pragma unroll
          for (int j = 0; j < 4; ++j)
            bv[kc % 3][j] = load4bf(wb + (size_t)(32 * j) * ND, kn, ND);
        }
      }

      short8 af[2], bq[4];
#pragma unroll
      for (int tm = 0; tm < 2; ++tm)
        af[tm] = *(const short8*)&As[kc][wm * 32 + tm * 16 + lr][lq * 8];
#pragma unroll
      for (int tn = 0; tn < 4; ++tn)
        bq[tn] = *(const short8*)&Bs[bi][wn * 64 + tn * 16 + lr][lq * 8];
#pragma unroll
      for (int tm = 0; tm < 2; ++tm)
#pragma unroll
        for (int tn = 0; tn < 4; ++tn)
          acc[tm][tn] =
              __builtin_amdgcn_mfma_f32_16x16x32_bf16(af[tm], bq[tn], acc[tm][tn], 0, 0, 0);
      BARRIER_LGKM();
    }

    // preload next pass's chunks 0-2 (slots all free after kc=8's write)
    if (nt < 3) {
      const XT* wb2 = Wih + (size_t)((nt + 1) * 128 + rb) * ND;
#pragma unroll
      for (int s3 = 0; s3 < 3; ++s3)
#pragma unroll
        for (int j = 0; j < 4; ++j)
          bv[s3][j] = load4bf_fast(wb2 + (size_t)(32 * j) * ND, s3 * 32 + kq * 4);
    }

    // Epilogue: add bias (bih+bhh) per output column, store.
    // C/D layout: col = lane&15, row = (lane>>4)*4 + reg
    float bias_c[4];
#pragma unroll
    for (int tn = 0; tn < 4; ++tn) {
      const int col = n0 + wn * 64 + tn * 16 + lr;
      bias_c[tn] = ld1(bih + col) + ld1(bhh + col);
    }
#pragma unroll
    for (int tm = 0; tm < 2; ++tm)
#pragma unroll
      for (int tn = 0; tn < 4; ++tn)
#pragma unroll
        for (int rg = 0; rg < 4; ++rg) {
          const int row = wm * 32 + tm * 16 + lq * 4 + rg;
          if (t0 + row < len) {
            const int col = n0 + wn * 64 + tn * 16 + lr;
            st1(gx + (size_t)(m0 + row) * NG + col, acc[tm][tn][rg] + bias_c[tn]);
          }
        }
  }
}

// ---------------------------------------------------------------------------
// Phase 2 body: per-batch recurrence via MFMA matvec. Round-2 structure
// (lgkm-only per-step barrier, static-parity gx prefetch slots, unroll-2).
// THIS ROUND: the 4 K-chunk MFMAs per gate are INDEPENDENT (accumulate from
// zero) and tree-added afterwards -- removes up to 3x MFMA dep-to-dep
// latency from the serial step chain for +3 f32x4 adds/gate in a 26%-busy
// VALU. (The step was 1150 cyc vs ~500 issue-side model; the gap is
// consistent with a long MFMA dependency latency.)
// ---------------------------------------------------------------------------
template <typename XT, typename GXT>
static __device__ __forceinline__ void rec_body(
    const GXT* __restrict__ gx, const XT* __restrict__ Whh,
    const XT* __restrict__ fcw, const XT* __restrict__ fcb,
    const int* __restrict__ lengths, XT* __restrict__ out,
    float* __restrict__ hstate, float* __restrict__ cstate,
    int b_base, int t_base, int Tc,
    unsigned short (*hpk)[NH], float* hf) {
  const int bc = blockIdx.x;
  const int b = b_base + bc;
  int len = lengths[b];
  if (len > NT) len = NT;
  if (len < 0) len = 0;
  const bool first = (t_base == 0);
  const bool last = (t_base + Tc >= NT);
  const int tend = (len < t_base + Tc) ? len : (t_base + Tc);
  if (!last && tend <= t_base) return;  // no steps; ws state untouched
  int nsteps = tend - t_base;
  if (nsteps < 0) nsteps = 0;

  const int tid = threadIdx.x;
  const int w8 = tid >> 6;         // wave: units [w8*16, w8*16+16)
  const int l = tid & 63;
  const int q = l >> 4;            // quad group
  const int m = l & 15;            // A-frag row select / D column id
  const int u0 = w8 * 16 + q * 4;  // first unit of this lane's D rows
  const int r = m & 3;             // unit handled by this lane
  const int u = u0 + r;

  // A fragments: afr[g][c] = W_hh[g*128 + w8*16 + m][c*32 + q*8 .. +8]
  short8 afr[4][4];
#pragma unroll
  for (int g = 0; g < 4; ++g) {
    const int row = g * NH + w8 * 16 + m;
    if constexpr (std::is_same_v<XT, unsigned short>) {
#pragma unroll
      for (int c = 0; c < 4; ++c)
        afr[g][c] = *(const short8*)(Whh + (size_t)row * NH + c * 32 + q * 8);
    } else {
#pragma unroll
      for (int c = 0; c < 4; ++c) {
        const float* p = Whh + (size_t)row * NH + c * 32 + q * 8;
        float4 f0 = *(const float4*)p;
        float4 f1 = *(const float4*)(p + 4);
        union { unsigned int uu[4]; short8 s; } cv2;
        cv2.uu[0] = packbf(f0.x, f0.y);
        cv2.uu[1] = packbf(f0.z, f0.w);
        cv2.uu[2] = packbf(f1.x, f1.y);
        cv2.uu[3] = packbf(f1.z, f1.w);
        afr[g][c] = cv2.s;
      }
    }
  }

  float hcur = 0.f, ccur = 0.f;
  if (!first) {
    hcur = hstate[(size_t)bc * NH + u];
    ccur = cstate[(size_t)bc * NH + u];
  }
  if (m < 4) hpk[0][u] = f2bf(hcur);
  __syncthreads();

  // gx pointers for this lane's unit: 4 gates at offsets g*128
  const GXT* gp = gx + (size_t)bc * Tc * NG + u;
  const int lastidx = (nsteps > 0) ? nsteps - 1 : 0;

  // static-parity prefetch slots: gs0 = even steps, gs1 = odd steps
  float gs0[4], gs1[4];
  {
    const int i1 = (1 < lastidx) ? 1 : lastidx;
#pragma unroll
    for (int g = 0; g < 4; ++g) {
      gs0[g] = ld1(gp + g * NH);
      gs1[g] = ld1(gp + (size_t)i1 * NG + g * NH);
    }
  }

  // One LSTM step. PAR compile-time 0/1: read hpk[PAR], write hpk[PAR^1].
  // GC consumed then reloaded with step S+2's gx row (waited 2 steps later).
  // The 4 K-chunk MFMAs per gate accumulate independently from zero and are
  // tree-added: chain = 1 MFMA latency + 2 add levels (was 4 MFMA latencies).
#define REC_STEP(S, PAR, GC)                                                         \
  {                                                                                  \
    short8 bfr[4];                                                                   \
    const unsigned short* hrow = hpk[(PAR)];                                         \
    _Pragma("unroll") for (int c = 0; c < 4; ++c)                                    \
        bfr[c] = *(const short8*)&hrow[c * 32 + q * 8];                              \
    const f32x4 zz = {0.f, 0.f, 0.f, 0.f};                                           \
    f32x4 acc[4];                                                                    \
    _Pragma("unroll") for (int g = 0; g < 4; ++g) {                                  \
      f32x4 p0 = __builtin_amdgcn_mfma_f32_16x16x32_bf16(afr[g][0], bfr[0], zz, 0, 0, 0); \
      f32x4 p1 = __builtin_amdgcn_mfma_f32_16x16x32_bf16(afr[g][1], bfr[1], zz, 0, 0, 0); \
      f32x4 p2 = __builtin_amdgcn_mfma_f32_16x16x32_bf16(afr[g][2], bfr[2], zz, 0, 0, 0); \
      f32x4 p3 = __builtin_amdgcn_mfma_f32_16x16x32_bf16(afr[g][3], bfr[3], zz, 0, 0, 0); \
      acc[g] = (p0 + p1) + (p2 + p3);                                                \
    }                                                                                \
    float pre[4];                                                                    \
    _Pragma("unroll") for (int g = 0; g < 4; ++g) {                                  \
      const float t0v = (r & 1) ? acc[g][1] : acc[g][0];                             \
      const float t1v = (r & 1) ? acc[g][3] : acc[g][2];                             \
      pre[g] = ((r & 2) ? t1v : t0v) + GC[g];                                        \
    }                                                                                \
    {                                                                                \
      int idx_ = (S) + 2;                                                            \
      if (idx_ > lastidx) idx_ = lastidx;                                            \
      _Pragma("unroll") for (int g = 0; g < 4; ++g)                                  \
          GC[g] = ld1(gp + (size_t)idx_ * NG + g * NH);                              \
    }                                                                                \
    const float ig = sigmoid_fast(pre[0]);                                           \
    const float fg = sigmoid_fast(pre[1]);                                           \
    const float gg = tanh_fast(pre[2]);                                              \
    const float og = sigmoid_fast(pre[3]);                                           \
    ccur = fmaf(fg, ccur, ig * gg);                                                  \
    hcur = og * tanh_fast(ccur);                                                     \
    if (m < 4) hpk[(PAR) ^ 1][u] = f2bf(hcur);                                       \
    BARRIER_LGKM();                                                                  \
  }

  int s = 0;
  for (; s + 1 < nsteps; s += 2) {
    REC_STEP(s, 0, gs0);
    REC_STEP(s + 1, 1, gs1);
  }
  if (s < nsteps) {
    REC_STEP(s, 0, gs0);
  }
#undef REC_STEP

  if (!last) {
    if (m < 4) {
      hstate[(size_t)bc * NH + u] = hcur;
      cstate[(size_t)bc * NH + u] = ccur;
    }
  } else {
    if (m < 4) hf[u] = hcur;
    __syncthreads();
    if (tid < NC) {
      float acc = ld1(fcb + tid);
      const XT* wv = fcw + (size_t)tid * NH;
#pragma unroll
      for (int k = 0; k < NH; ++k) acc = fmaf(ld1(wv + k), hf[k], acc);
      st1(out + (size_t)b * NC + tid, acc);
    }
  }
}

// ---------------------------------------------------------------------------
// Runtime-dtype kernels: one launch each, both typed bodies inlined; the
// uniform per-block flag picks the path. GXT stays a compile-time template
// (host knows the workspace size).
// ---------------------------------------------------------------------------
template <typename GXT>
__global__ __launch_bounds__(256) void gx_gemm_rt(const void* __restrict__ X,
                                                  const void* __restrict__ Wih,
                                                  const void* __restrict__ bih,
                                                  const void* __restrict__ bhh,
                                                  const int* __restrict__ lengths,
                                                  GXT* __restrict__ gx,
                                                  int b_base, int t_base, int Tc) {
  __shared__ int cnt;
  __shared__ __align__(16) unsigned short smem[35840];  // As 50K + Bs 20K
  const int isf32 = block_detect((const unsigned short*)X, &cnt);
  if (isf32)
    gx_body<float, GXT>((const float*)X, (const float*)Wih, (const float*)bih,
                        (const float*)bhh, lengths, gx, b_base, t_base, Tc, smem);
  else
    gx_body<unsigned short, GXT>((const unsigned short*)X, (const unsigned short*)Wih,
                                 (const unsigned short*)bih, (const unsigned short*)bhh,
                                 lengths, gx, b_base, t_base, Tc, smem);
}

template <typename GXT>
__global__ __launch_bounds__(512)
__attribute__((amdgpu_waves_per_eu(2, 2)))
void lstm_rec_rt(const void* __restrict__ X, const GXT* __restrict__ gx,
                 const void* __restrict__ Whh, const void* __restrict__ fcw,
                 const void* __restrict__ fcb, const int* __restrict__ lengths,
                 void* __restrict__ out, float* __restrict__ hstate,
                 float* __restrict__ cstate, int b_base, int t_base, int Tc) {
  __shared__ int cnt;
  __shared__ __align__(16) unsigned short hpk[2][NH];
  __shared__ __align__(16) float hf[NH];
  const int isf32 = block_detect((const unsigned short*)X, &cnt);
  if (isf32)
    rec_body<float, GXT>(gx, (const float*)Whh, (const float*)fcw, (const float*)fcb,
                         lengths, (float*)out, hstate, cstate, b_base, t_base, Tc,
                         hpk, hf);
  else
    rec_body<unsigned short, GXT>(gx, (const unsigned short*)Whh,
                                  (const unsigned short*)fcw,
                                  (const unsigned short*)fcb, lengths,
                                  (unsigned short*)out, hstate, cstate, b_base,
                                  t_base, Tc, hpk, hf);
}

// ---------------------------------------------------------------------------
template <typename GXT>
static void run_all(void* const* d_in, void* d_out, GXT* gx, float* hstate,
                    float* cstate, int NBc, int Tc, hipStream_t stream) {
  const int* lengths = (const int*)d_in[7];
  for (int bb = 0; bb < NB; bb += NBc) {
    for (int tb = 0; tb < NT; tb += Tc) {
      gx_gemm_rt<GXT><<<dim3((NBc * Tc) / 64), dim3(256), 0, stream>>>(
          d_in[0], d_in[1], d_in[3], d_in[4], lengths, gx, bb, tb, Tc);
      lstm_rec_rt<GXT><<<dim3(NBc), dim3(512), 0, stream>>>(
          d_in[0], gx, d_in[2], d_in[5], d_in[6], lengths, d_out, hstate, cstate,
          bb, tb, Tc);
    }
  }
}

extern "C" void kernel_launch(void* const* d_in, const int* in_sizes, int n_in,
                              void* d_out, int out_size, void* d_ws, size_t ws_size,
                              hipStream_t stream) {
  const size_t full_f32 = (size_t)NB * NT * NG * sizeof(float);
  const size_t full_bf16 = (size_t)NB * NT * NG * 2;
  const size_t base = 512;

  int NBc, Tc;
  char* gx_raw;
  float* hstate = (float*)((char*)d_ws + base);
  bool gx_is_f32;

  if (ws_size >= base + full_f32) {
    NBc = NB; Tc = NT; gx_is_f32 = true;
    gx_raw = (char*)d_ws + base;  // hstate unused in the single-chunk path
  } else if (ws_size >= base + full_bf16) {
    NBc = NB; Tc = NT; gx_is_f32 = false;
    gx_raw = (char*)d_ws + base;
  } else {
    Tc = 128; gx_is_f32 = false;
    NBc = 1;
    for (int cand : {64, 16, 4}) {
      size_t need = base + (size_t)cand * NH * 2 * sizeof(float) + (size_t)cand * Tc * NG * 2;
      if (ws_size >= need) { NBc = cand; break; }
    }
    gx_raw = (char*)d_ws + base + (size_t)NBc * NH * 2 * sizeof(float);
  }
  float* cstate = hstate + (size_t)NBc * NH;

  if (gx_is_f32) {
    run_all<float>(d_in, d_out, (float*)gx_raw, hstate, cstate, NBc, Tc, stream);
  } else {
    run_all<unsigned short>(d_in, d_out, (unsigned short*)gx_raw, hstate, cstate,
                            NBc, Tc, stream);
  }
}

// Round 6
// 580.001 us; speedup vs baseline: 1.3349x; 1.2247x over previous
//
#include <hip/hip_runtime.h>
#include <hip/hip_bf16.h>
#include <stdint.h>
#include <type_traits>

// Problem constants: B=256, T=512, D=300, H=128, 4H=512, C=6
#define NB 256
#define NT 512
#define ND 300
#define NH 128
#define NG 512
#define NC 6

typedef __attribute__((ext_vector_type(8))) short short8;
typedef __attribute__((ext_vector_type(4))) float f32x4;

static __device__ __forceinline__ float bf2f(unsigned int u) {
  return __builtin_bit_cast(float, (u & 0xffffu) << 16);
}
static __device__ __forceinline__ unsigned short f2bf(float f) {
  return __builtin_bit_cast(unsigned short, __float2bfloat16(f));
}
static __device__ __forceinline__ unsigned int packbf(float a, float b) {
  return (unsigned int)f2bf(a) | ((unsigned int)f2bf(b) << 16);
}
static __device__ __forceinline__ float ld1(const unsigned short* p) { return bf2f(*p); }
static __device__ __forceinline__ float ld1(const float* p) { return *p; }
static __device__ __forceinline__ void st1(unsigned short* p, float v) { *p = f2bf(v); }
static __device__ __forceinline__ void st1(float* p, float v) { *p = v; }

static __device__ __forceinline__ float sigmoid_fast(float x) {
  return __builtin_amdgcn_rcpf(1.f + __expf(-x));
}
static __device__ __forceinline__ float tanh_fast(float x) {
  return 1.f - 2.f * __builtin_amdgcn_rcpf(__expf(2.f * x) + 1.f);
}

// Barrier that does NOT drain vmcnt: LDS ordering only (T4 idiom).
#define BARRIER_LGKM() asm volatile("s_waitcnt lgkmcnt(0)\n\ts_barrier" ::: "memory")

// ---- staging loads: 4 K-elems -> 2 packed bf16 pairs ------------------------
static __device__ __forceinline__ uint2 load4bf_fast(const unsigned short* row, int k) {
  return *(const uint2*)(row + k);
}
static __device__ __forceinline__ uint2 load4bf_fast(const float* row, int k) {
  float4 f = *(const float4*)(row + k);
  uint2 v;
  v.x = packbf(f.x, f.y);
  v.y = packbf(f.z, f.w);
  return v;
}
static __device__ __forceinline__ uint2 load4bf(const unsigned short* row, int k, int lim) {
  if (k + 3 < lim) return load4bf_fast(row, k);
  unsigned int e0 = (k + 0 < lim) ? row[k + 0] : 0;
  unsigned int e1 = (k + 1 < lim) ? row[k + 1] : 0;
  unsigned int e2 = (k + 2 < lim) ? row[k + 2] : 0;
  unsigned int e3 = (k + 3 < lim) ? row[k + 3] : 0;
  uint2 v;
  v.x = e0 | (e1 << 16);
  v.y = e2 | (e3 << 16);
  return v;
}
static __device__ __forceinline__ uint2 load4bf(const float* row, int k, int lim) {
  if (k + 3 < lim) return load4bf_fast(row, k);
  float f0 = (k + 0 < lim) ? row[k + 0] : 0.f;
  float f1 = (k + 1 < lim) ? row[k + 1] : 0.f;
  float f2 = (k + 2 < lim) ? row[k + 2] : 0.f;
  float f3 = (k + 3 < lim) ? row[k + 3] : 0.f;
  uint2 v;
  v.x = packbf(f0, f1);
  v.y = packbf(f2, f3);
  return v;
}

// ---------------------------------------------------------------------------
// Per-block dtype self-detect (0 = bf16 inputs, 1 = fp32 inputs).
// ---------------------------------------------------------------------------
static __device__ __forceinline__ int block_detect(const unsigned short* __restrict__ X,
                                                   int* cnt) {
  const int tid = threadIdx.x;
  const int nthr = blockDim.x;
  if (tid == 0) *cnt = 0;
  __syncthreads();
  int c = 0;
  for (int i = tid; i < 512; i += nthr) {
    unsigned int u = X[i];
    unsigned int e = (u >> 7) & 0xffu;
    if (u == 0u || (e >= 97u && e <= 157u)) c++;
  }
  if (c) atomicAdd(cnt, c);
  __syncthreads();
  return (*cnt >= 448) ? 0 : 1;
}

// ---------------------------------------------------------------------------
// gx producer tile: 64 t-rows x all 512 gates for one batch window.
// 512 threads / 8 waves (2 t-strips x 4 n-strips of 32). Round-2 K-loop
// structure (full-K A staged once, W double-buffered, lgkm-only barriers,
// distance-3 register prefetch). MFMA operands SWAPPED vs round 2
// (A=W frag, B=x frag) so D is [gate][t]: each lane's f32x4 accumulator =
// 4 CONSECUTIVE gate columns -> f32x4 stores (4x fewer store insts, wider
// segments). Verified against m89 C/D layout: D row (lq*4+rg) = gate,
// D col (lr) = t-row. Same product set as round 2 -> same numerics.
// ---------------------------------------------------------------------------
template <typename XT, typename GXT>
static __device__ __forceinline__ void gx_prod(
    const XT* __restrict__ X, const XT* __restrict__ Wih,
    const XT* __restrict__ bih, const XT* __restrict__ bhh,
    int b, int t0, int len, GXT* __restrict__ gxrow, unsigned short* smem) {
  auto As = reinterpret_cast<unsigned short(*)[64][40]>(smem);           // [10][64][40]
  auto Bs = reinterpret_cast<unsigned short(*)[128][40]>(smem + 25600);  // [2][128][40]

  const int tid = threadIdx.x;
  const int lane = tid & 63;
  const int wave = tid >> 6;
  const int wt = wave & 1;   // t-strip of 32
  const int wn4 = wave >> 1; // n-strip of 32 (within 128-col pass)
  const int lq = lane >> 4;
  const int lr = lane & 15;

  // ---- stage A (x): 64 rows x 320 k, once. 8 threads/row -----------------
  const int rA = tid >> 3;
  const int cA = (tid & 7) << 2;
  const XT* xrow = X + ((size_t)b * NT + t0 + rA) * ND;
  {
    uint2 a[10];
#pragma unroll
    for (int kc = 0; kc < 9; ++kc) a[kc] = load4bf_fast(xrow, kc * 32 + cA);
    a[9] = load4bf(xrow, 288 + cA, ND);
#pragma unroll
    for (int kc = 0; kc < 10; ++kc) *(uint2*)&As[kc][rA][cA] = a[kc];
  }

  // ---- W stream: 4 threads/row, 8 k each ---------------------------------
  const int rb = tid >> 2;
  const int kqo = (tid & 3) << 3;
  uint2 bv[3][2];
  {
    const XT* wb = Wih + (size_t)rb * ND;  // pass 0
#pragma unroll
    for (int s3 = 0; s3 < 3; ++s3) {
      bv[s3][0] = load4bf_fast(wb, s3 * 32 + kqo);
      bv[s3][1] = load4bf_fast(wb, s3 * 32 + kqo + 4);
    }
  }

  for (int nt = 0; nt < 4; ++nt) {
    const int n0 = nt << 7;
    const XT* wb = Wih + (size_t)(n0 + rb) * ND;

    f32x4 acc[2][2];
#pragma unroll
    for (int i = 0; i < 2; ++i)
#pragma unroll
      for (int j = 0; j < 2; ++j) {
        f32x4 z = {0.f, 0.f, 0.f, 0.f};
        acc[i][j] = z;
      }

    *(uint2*)&Bs[0][rb][kqo] = bv[0][0];
    *(uint2*)&Bs[0][rb][kqo + 4] = bv[0][1];
    BARRIER_LGKM();

#pragma unroll
    for (int kc = 0; kc < 10; ++kc) {
      const int bi = kc & 1;
      if (kc < 9) {
        *(uint2*)&Bs[bi ^ 1][rb][kqo] = bv[(kc + 1) % 3][0];
        *(uint2*)&Bs[bi ^ 1][rb][kqo + 4] = bv[(kc + 1) % 3][1];
      }
      if (kc < 7) {
        const int kn = (kc + 3) * 32 + kqo;
        if (kc < 6) {
          bv[kc % 3][0] = load4bf_fast(wb, kn);
          bv[kc % 3][1] = load4bf_fast(wb, kn + 4);
        } else {  // chunk 9: 288..319 masked at 300
          bv[kc % 3][0] = load4bf(wb, kn, ND);
          bv[kc % 3][1] = load4bf(wb, kn + 4, ND);
        }
      }

      short8 wF[2], aX[2];
#pragma unroll
      for (int tn = 0; tn < 2; ++tn)
        wF[tn] = *(const short8*)&Bs[bi][wn4 * 32 + tn * 16 + lr][lq * 8];
#pragma unroll
      for (int tt = 0; tt < 2; ++tt)
        aX[tt] = *(const short8*)&As[kc][wt * 32 + tt * 16 + lr][lq * 8];
#pragma unroll
      for (int tt = 0; tt < 2; ++tt)
#pragma unroll
        for (int tn = 0; tn < 2; ++tn)
          acc[tt][tn] =
              __builtin_amdgcn_mfma_f32_16x16x32_bf16(wF[tn], aX[tt], acc[tt][tn], 0, 0, 0);
      BARRIER_LGKM();
    }

    if (nt < 3) {
      const XT* wb2 = Wih + (size_t)((nt + 1) * 128 + rb) * ND;
#pragma unroll
      for (int s3 = 0; s3 < 3; ++s3) {
        bv[s3][0] = load4bf_fast(wb2, s3 * 32 + kqo);
        bv[s3][1] = load4bf_fast(wb2, s3 * 32 + kqo + 4);
      }
    }

    // Epilogue: D row (lq*4+rg) = gate col n; D col (lr) = t row.
    f32x4 bias4[2];
#pragma unroll
    for (int tn = 0; tn < 2; ++tn) {
      const int n = n0 + wn4 * 32 + tn * 16 + lq * 4;
#pragma unroll
      for (int rg = 0; rg < 4; ++rg) bias4[tn][rg] = ld1(bih + n + rg) + ld1(bhh + n + rg);
    }
#pragma unroll
    for (int tt = 0; tt < 2; ++tt) {
      const int trow = wt * 32 + tt * 16 + lr;
      if (t0 + trow < len) {
#pragma unroll
        for (int tn = 0; tn < 2; ++tn) {
          const int n = n0 + wn4 * 32 + tn * 16 + lq * 4;
          f32x4 o = acc[tt][tn] + bias4[tn];
          if constexpr (std::is_same_v<GXT, float>) {
            *(f32x4*)(gxrow + (size_t)trow * NG + n) = o;
          } else {
            uint2 v;
            v.x = packbf(o[0], o[1]);
            v.y = packbf(o[2], o[3]);
            *(uint2*)(gxrow + (size_t)trow * NG + n) = v;
          }
        }
      }
    }
  }
}

// ---------------------------------------------------------------------------
// One LSTM step -- EXACT round-2 structure (chained MFMA accumulation;
// round 4's tree-add regressed 267->413us via MFMA->VALU read-back latency).
// PAR compile-time 0/1; GC reloaded with step S+2's gx row, clamped to CAP.
// ---------------------------------------------------------------------------
#define REC_STEP(S, PAR, GC, CAP)                                                    \
  {                                                                                  \
    short8 bfr[4];                                                                   \
    const unsigned short* hrow = hpk[(PAR)];                                         \
    _Pragma("unroll") for (int c = 0; c < 4; ++c)                                    \
        bfr[c] = *(const short8*)&hrow[c * 32 + q * 8];                              \
    f32x4 acc[4];                                                                    \
    _Pragma("unroll") for (int g = 0; g < 4; ++g) {                                  \
      f32x4 z = {0.f, 0.f, 0.f, 0.f};                                                \
      acc[g] = z;                                                                    \
      _Pragma("unroll") for (int c = 0; c < 4; ++c)                                  \
          acc[g] = __builtin_amdgcn_mfma_f32_16x16x32_bf16(afr[g][c], bfr[c],        \
                                                           acc[g], 0, 0, 0);         \
    }                                                                                \
    float pre[4];                                                                    \
    _Pragma("unroll") for (int g = 0; g < 4; ++g) {                                  \
      const float t0v = (r & 1) ? acc[g][1] : acc[g][0];                             \
      const float t1v = (r & 1) ? acc[g][3] : acc[g][2];                             \
      pre[g] = ((r & 2) ? t1v : t0v) + GC[g];                                        \
    }                                                                                \
    {                                                                                \
      int idx_ = (S) + 2;                                                            \
      if (idx_ > (CAP)) idx_ = (CAP);                                                \
      _Pragma("unroll") for (int g = 0; g < 4; ++g)                                  \
          GC[g] = ld1(gp + (size_t)idx_ * NG + g * NH);                              \
    }                                                                                \
    const float ig = sigmoid_fast(pre[0]);                                           \
    const float fg = sigmoid_fast(pre[1]);                                           \
    const float gg = tanh_fast(pre[2]);                                              \
    const float og = sigmoid_fast(pre[3]);                                           \
    ccur = fmaf(fg, ccur, ig * gg);                                                  \
    hcur = og * tanh_fast(ccur);                                                     \
    if (m < 4) hpk[(PAR) ^ 1][u] = f2bf(hcur);                                       \
    BARRIER_LGKM();                                                                  \
  }

// ---------------------------------------------------------------------------
// rec A-fragment load: afr[g][c] = W_hh[g*128+w8*16+m][c*32+q*8..+8]
// ---------------------------------------------------------------------------
template <typename XT>
static __device__ __forceinline__ void load_afr(const XT* __restrict__ Whh, int w8,
                                                int q, int m, short8 afr[4][4]) {
#pragma unroll
  for (int g = 0; g < 4; ++g) {
    const int row = g * NH + w8 * 16 + m;
    if constexpr (std::is_same_v<XT, unsigned short>) {
#pragma unroll
      for (int c = 0; c < 4; ++c)
        afr[g][c] = *(const short8*)(Whh + (size_t)row * NH + c * 32 + q * 8);
    } else {
#pragma unroll
      for (int c = 0; c < 4; ++c) {
        const float* p = Whh + (size_t)row * NH + c * 32 + q * 8;
        float4 f0 = *(const float4*)p;
        float4 f1 = *(const float4*)(p + 4);
        union { unsigned int uu[4]; short8 s; } cv2;
        cv2.uu[0] = packbf(f0.x, f0.y);
        cv2.uu[1] = packbf(f0.z, f0.w);
        cv2.uu[2] = packbf(f1.x, f1.y);
        cv2.uu[3] = packbf(f1.z, f1.w);
        afr[g][c] = cv2.s;
      }
    }
  }
}

// ---------------------------------------------------------------------------
// Phase 2 body: per-batch recurrence via MFMA matvec -- EXACT round-2
// structure (measured 267us): lgkm-only per-step barrier, static-parity gx
// prefetch slots (gs0/gs1, unroll-2), chained MFMA accumulation.
// ---------------------------------------------------------------------------
template <typename XT, typename GXT>
static __device__ __forceinline__ void rec_body(
    const GXT* __restrict__ gx, const XT* __restrict__ Whh,
    const XT* __restrict__ fcw, const XT* __restrict__ fcb,
    const int* __restrict__ lengths, XT* __restrict__ out,
    float* __restrict__ hstate, float* __restrict__ cstate,
    int b_base, int t_base, int Tc,
    unsigned short (*hpk)[NH], float* hf) {
  const int bc = blockIdx.x;
  const int b = b_base + bc;
  int len = lengths[b];
  if (len > NT) len = NT;
  if (len < 0) len = 0;
  const bool first = (t_base == 0);
  const bool last = (t_base + Tc >= NT);
  const int tend = (len < t_base + Tc) ? len : (t_base + Tc);
  if (!last && tend <= t_base) return;
  int nsteps = tend - t_base;
  if (nsteps < 0) nsteps = 0;

  const int tid = threadIdx.x;
  const int w8 = tid >> 6;
  const int l = tid & 63;
  const int q = l >> 4;
  const int m = l & 15;
  const int u0 = w8 * 16 + q * 4;
  const int r = m & 3;
  const int u = u0 + r;

  short8 afr[4][4];
  load_afr<XT>(Whh, w8, q, m, afr);

  float hcur = 0.f, ccur = 0.f;
  if (!first) {
    hcur = hstate[(size_t)bc * NH + u];
    ccur = cstate[(size_t)bc * NH + u];
  }
  if (m < 4) hpk[0][u] = f2bf(hcur);
  __syncthreads();

  const GXT* gp = gx + (size_t)bc * Tc * NG + u;
  const int lastidx = (nsteps > 0) ? nsteps - 1 : 0;

  float gs0[4], gs1[4];
  {
    const int i1 = (1 < lastidx) ? 1 : lastidx;
#pragma unroll
    for (int g = 0; g < 4; ++g) {
      gs0[g] = ld1(gp + g * NH);
      gs1[g] = ld1(gp + (size_t)i1 * NG + g * NH);
    }
  }

  int s = 0;
  for (; s + 1 < nsteps; s += 2) {
    REC_STEP(s, 0, gs0, lastidx);
    REC_STEP(s + 1, 1, gs1, lastidx);
  }
  if (s < nsteps) {
    REC_STEP(s, 0, gs0, lastidx);
  }

  if (!last) {
    if (m < 4) {
      hstate[(size_t)bc * NH + u] = hcur;
      cstate[(size_t)bc * NH + u] = ccur;
    }
  } else {
    if (m < 4) hf[u] = hcur;
    __syncthreads();
    if (tid < NC) {
      float acc = ld1(fcb + tid);
      const XT* wv = fcw + (size_t)tid * NH;
#pragma unroll
      for (int k = 0; k < NH; ++k) acc = fmaf(ld1(wv + k), hf[k], acc);
      st1(out + (size_t)b * NC + tid, acc);
    }
  }
}

// ---------------------------------------------------------------------------
// Runtime-dtype kernels (2 launches per invocation total).
// ---------------------------------------------------------------------------
template <typename GXT>
__global__ __launch_bounds__(512, 4) void gx_gemm_rt(const void* __restrict__ X,
                                                     const void* __restrict__ Wih,
                                                     const void* __restrict__ bih,
                                                     const void* __restrict__ bhh,
                                                     const int* __restrict__ lengths,
                                                     GXT* __restrict__ gx,
                                                     int b_base, int t_base, int Tc) {
  __shared__ int cnt;
  __shared__ __align__(16) unsigned short smem[35840];  // As 50K + Bs 20K
  const int isf32 = block_detect((const unsigned short*)X, &cnt);
  const int m0 = blockIdx.x << 6;
  const int bc = m0 / Tc;
  const int trel = m0 % Tc;
  const int b = b_base + bc;
  const int t0 = t_base + trel;
  int len = lengths[b];
  if (len > NT) len = NT;
  if (t0 >= len) return;  // block-uniform
  GXT* gxrow = gx + (size_t)m0 * NG;
  if (isf32)
    gx_prod<float, GXT>((const float*)X, (const float*)Wih, (const float*)bih,
                        (const float*)bhh, b, t0, len, gxrow, smem);
  else
    gx_prod<unsigned short, GXT>((const unsigned short*)X, (const unsigned short*)Wih,
                                 (const unsigned short*)bih, (const unsigned short*)bhh,
                                 b, t0, len, gxrow, smem);
}

template <typename GXT>
__global__ __launch_bounds__(512)
__attribute__((amdgpu_waves_per_eu(2, 2)))
void lstm_rec_rt(const void* __restrict__ X, const GXT* __restrict__ gx,
                 const void* __restrict__ Whh, const void* __restrict__ fcw,
                 const void* __restrict__ fcb, const int* __restrict__ lengths,
                 void* __restrict__ out, float* __restrict__ hstate,
                 float* __restrict__ cstate, int b_base, int t_base, int Tc) {
  __shared__ int cnt;
  __shared__ __align__(16) unsigned short hpk[2][NH];
  __shared__ __align__(16) float hf[NH];
  const int isf32 = block_detect((const unsigned short*)X, &cnt);
  if (isf32)
    rec_body<float, GXT>(gx, (const float*)Whh, (const float*)fcw, (const float*)fcb,
                         lengths, (float*)out, hstate, cstate, b_base, t_base, Tc,
                         hpk, hf);
  else
    rec_body<unsigned short, GXT>(gx, (const unsigned short*)Whh,
                                  (const unsigned short*)fcw,
                                  (const unsigned short*)fcb, lengths,
                                  (unsigned short*)out, hstate, cstate, b_base,
                                  t_base, Tc, hpk, hf);
}

// ---------------------------------------------------------------------------
template <typename GXT>
static void run_all(void* const* d_in, void* d_out, GXT* gx, float* hstate,
                    float* cstate, int NBc, int Tc, hipStream_t stream) {
  const int* lengths = (const int*)d_in[7];
  for (int bb = 0; bb < NB; bb += NBc) {
    for (int tb = 0; tb < NT; tb += Tc) {
      gx_gemm_rt<GXT><<<dim3((NBc * Tc) / 64), dim3(512), 0, stream>>>(
          d_in[0], d_in[1], d_in[3], d_in[4], lengths, gx, bb, tb, Tc);
      lstm_rec_rt<GXT><<<dim3(NBc), dim3(512), 0, stream>>>(
          d_in[0], gx, d_in[2], d_in[5], d_in[6], lengths, d_out, hstate, cstate,
          bb, tb, Tc);
    }
  }
}

extern "C" void kernel_launch(void* const* d_in, const int* in_sizes, int n_in,
                              void* d_out, int out_size, void* d_ws, size_t ws_size,
                              hipStream_t stream) {
  const size_t full_f32 = (size_t)NB * NT * NG * sizeof(float);
  const size_t full_bf16 = (size_t)NB * NT * NG * 2;
  const size_t base = 512;

  int NBc, Tc;
  char* gx_raw;
  float* hstate = (float*)((char*)d_ws + base);
  bool gx_is_f32;

  if (ws_size >= base + full_f32) {
    NBc = NB; Tc = NT; gx_is_f32 = true;
    gx_raw = (char*)d_ws + base;  // hstate unused in the single-chunk path
  } else if (ws_size >= base + full_bf16) {
    NBc = NB; Tc = NT; gx_is_f32 = false;
    gx_raw = (char*)d_ws + base;
  } else {
    Tc = 128; gx_is_f32 = false;
    NBc = 1;
    for (int cand : {64, 16, 4}) {
      size_t need = base + (size_t)cand * NH * 2 * sizeof(float) + (size_t)cand * Tc * NG * 2;
      if (ws_size >= need) { NBc = cand; break; }
    }
    gx_raw = (char*)d_ws + base + (size_t)NBc * NH * 2 * sizeof(float);
  }
  float* cstate = hstate + (size_t)NBc * NH;

  if (gx_is_f32) {
    run_all<float>(d_in, d_out, (float*)gx_raw, hstate, cstate, NBc, Tc, stream);
  } else {
    run_all<unsigned short>(d_in, d_out, (unsigned short*)gx_raw, hstate, cstate,
                            NBc, Tc, stream);
  }
}